// Round 5
// baseline (257.506 us; speedup 1.0000x reference)
//
#include <hip/hip_runtime.h>

#define D 128
#define ANSTR 136  // LDS row stride (shorts): 272B, 4-mod-32 bank class (proven)

typedef __attribute__((ext_vector_type(8))) short short8;
typedef __attribute__((ext_vector_type(4))) short short4v;
typedef __attribute__((ext_vector_type(4))) float f32x4;

// f32 -> bf16 round-to-nearest-even
__device__ inline unsigned short f2b(float f) {
    unsigned u = __float_as_uint(f);
    u += 0x7FFFu + ((u >> 16) & 1u);
    return (unsigned short)(u >> 16);
}
__device__ inline float b2f_lo(unsigned v) { return __uint_as_float(v << 16); }
__device__ inline float b2f_hi(unsigned v) { return __uint_as_float(v & 0xFFFF0000u); }

// ---------------- combined prep (x->bf16, W transpose) + degree count ----------------

__global__ __launch_bounds__(256) void k_prep_count(
        const float* __restrict__ x, unsigned short* __restrict__ xb, int n,
        int nConvBlocks,
        const float* __restrict__ Ws0, const float* __restrict__ Wn0,
        const float* __restrict__ Ws1, const float* __restrict__ Wn1,
        unsigned short* __restrict__ WT0, unsigned short* __restrict__ WT1,
        const int* __restrict__ dst, int* __restrict__ cnt, int E) {
    int bid = blockIdx.x;
    if (bid < nConvBlocks) {
        int i = (bid * 256 + threadIdx.x) * 8;
        if (i >= n) return;
        float4 a = *(const float4*)&x[i];
        float4 b = *(const float4*)&x[i + 4];
        short8 v;
        v[0] = (short)f2b(a.x); v[1] = (short)f2b(a.y);
        v[2] = (short)f2b(a.z); v[3] = (short)f2b(a.w);
        v[4] = (short)f2b(b.x); v[5] = (short)f2b(b.y);
        v[6] = (short)f2b(b.z); v[7] = (short)f2b(b.w);
        *(short8*)&xb[i] = v;
    } else if (bid < nConvBlocks + 256) {
        int idx = (bid - nConvBlocks) * 256 + threadIdx.x;  // 0..65535
        int layer = idx >> 15;
        int r = idx & 32767;
        int k = r >> 7;
        int nn = r & 127;
        const float* Ws = layer ? Ws1 : Ws0;
        const float* Wn = layer ? Wn1 : Wn0;
        unsigned short* Wt = layer ? WT1 : WT0;
        float v = (k < 128) ? Ws[k * 128 + nn] : Wn[(k - 128) * 128 + nn];
        Wt[nn * 256 + k] = f2b(v);
    } else {
        int e = (bid - nConvBlocks - 256) * 256 + threadIdx.x;
        if (e < E) atomicAdd(&cnt[dst[e]], 1);
    }
}

// ---------------- CSR scan ----------------

__global__ __launch_bounds__(256) void k_scan_chunk(const int* __restrict__ cnt,
                                                    int* __restrict__ row_ptr,
                                                    int* __restrict__ partial, int N) {
    __shared__ int s[256];
    int t = threadIdx.x;
    int base = blockIdx.x * 2048 + t * 8;
    int v[8];
    int sum = 0;
#pragma unroll
    for (int i = 0; i < 8; ++i) {
        v[i] = sum;
        int idx = base + i;
        sum += (idx < N) ? cnt[idx] : 0;
    }
    s[t] = sum;
    __syncthreads();
    for (int off = 1; off < 256; off <<= 1) {
        int x = (t >= off) ? s[t - off] : 0;
        __syncthreads();
        s[t] += x;
        __syncthreads();
    }
    int exc = s[t] - sum;
#pragma unroll
    for (int i = 0; i < 8; ++i) {
        int idx = base + i;
        if (idx < N) row_ptr[idx] = exc + v[i];
    }
    if (t == 255) partial[blockIdx.x] = s[255];
}

__global__ __launch_bounds__(256) void k_scan_add(int* __restrict__ row_ptr,
                                                  int* __restrict__ cnt,
                                                  const int* __restrict__ partial,
                                                  int N, int nChunks) {
    __shared__ int soff;
    int chunk = blockIdx.x;
    if (threadIdx.x == 0) {
        int o = 0;
        for (int j = 0; j < chunk; ++j) o += partial[j];
        soff = o;
    }
    __syncthreads();
    int off = soff;
    int lo = chunk * 2048;
    int hi = (chunk + 1) * 2048; if (hi > N) hi = N;
    for (int i = lo + threadIdx.x; i < hi; i += 256) {
        int v = row_ptr[i] + off;
        row_ptr[i] = v;
        cnt[i] = v;  // cursor copy for k_fill
    }
    if (chunk == nChunks - 1 && threadIdx.x == 0) row_ptr[N] = off + partial[chunk];
}

__global__ __launch_bounds__(256) void k_fill(const int* __restrict__ src,
                                              const int* __restrict__ dst,
                                              int* __restrict__ cnt,
                                              int* __restrict__ col, int E) {
    int e = blockIdx.x * 256 + threadIdx.x;
    if (e >= E) return;
    int p = atomicAdd(&cnt[dst[e]], 1);
    col[p] = src[e];
}

// ---------------- fused agg + MFMA SAGE layer ----------------
// Block = 4 waves, 64 rows. Wave wid owns rows rowBase = blk*64 + wid*16 .. +16.
// Phase 1 (wave-private, no barrier): aggregate neighbors of own 16 rows into
//   LDS An tile (bf16, stride 136).
// Phase 2: MFMA over K=256: k<128 self rows (global), k>=128 An (LDS).
//   Swapped operands -> lane (l15,kq) holds row rowBase+l15, cols r*16+kq*4+j.
// mode 0: store relu(gemm+bias) as bf16 [N][128]
// mode 1: (final) v=relu(gemm+bias); out=v@Ws2+b2, p=v@Wn2 via kq-lane reduce.

__global__ __launch_bounds__(256) void k_fused(
        const unsigned short* __restrict__ h,
        const int* __restrict__ row_ptr,
        const int* __restrict__ col,
        const unsigned short* __restrict__ Wt,   // [128 n][256 k] bf16
        const float* __restrict__ bias,
        unsigned short* __restrict__ out_h,      // mode 0
        const float* __restrict__ Ws2,           // mode 1: [128][2]
        const float* __restrict__ Wn2,
        const float* __restrict__ b2,
        float* __restrict__ out_final,           // mode 1: [N][2]
        float* __restrict__ p,                   // mode 1: [N][2]
        int N, int mode) {
    __shared__ unsigned short An[64 * ANSTR];  // 17408 B
    int tid = threadIdx.x;
    int lane = tid & 63;
    int wid = tid >> 6;
    int rowBase = blockIdx.x * 64 + wid * 16;

    // ---- phase 1: aggregate own 16 rows (wave-private LDS region) ----
    int rp_lane = (lane < 17) ? row_ptr[min(rowBase + lane, N)] : 0;

    int beg = __shfl(rp_lane, 0), end = __shfl(rp_lane, 1);
    int deg = end - beg;
    int myc = (lane < deg) ? col[beg + lane] : 0;
    for (int r = 0; r < 16; ++r) {
        // prefetch next row's neighbor ids
        int begN = 0, endN = 0, degN = 0, mycN = 0;
        if (r < 15) {
            begN = __shfl(rp_lane, r + 1);
            endN = __shfl(rp_lane, r + 2);
            degN = endN - begN;
            mycN = (lane < degN) ? col[begN + lane] : 0;
        }
        float ax = 0.f, ay = 0.f;
        int d64 = min(deg, 64);
        int j = 0;
        for (; j + 8 <= d64; j += 8) {
            int s0 = __shfl(myc, j + 0), s1 = __shfl(myc, j + 1);
            int s2 = __shfl(myc, j + 2), s3 = __shfl(myc, j + 3);
            int s4 = __shfl(myc, j + 4), s5 = __shfl(myc, j + 5);
            int s6 = __shfl(myc, j + 6), s7 = __shfl(myc, j + 7);
            unsigned v0 = *(const unsigned*)&h[(size_t)s0 * D + lane * 2];
            unsigned v1 = *(const unsigned*)&h[(size_t)s1 * D + lane * 2];
            unsigned v2 = *(const unsigned*)&h[(size_t)s2 * D + lane * 2];
            unsigned v3 = *(const unsigned*)&h[(size_t)s3 * D + lane * 2];
            unsigned v4 = *(const unsigned*)&h[(size_t)s4 * D + lane * 2];
            unsigned v5 = *(const unsigned*)&h[(size_t)s5 * D + lane * 2];
            unsigned v6 = *(const unsigned*)&h[(size_t)s6 * D + lane * 2];
            unsigned v7 = *(const unsigned*)&h[(size_t)s7 * D + lane * 2];
            ax += ((b2f_lo(v0) + b2f_lo(v1)) + (b2f_lo(v2) + b2f_lo(v3)))
                + ((b2f_lo(v4) + b2f_lo(v5)) + (b2f_lo(v6) + b2f_lo(v7)));
            ay += ((b2f_hi(v0) + b2f_hi(v1)) + (b2f_hi(v2) + b2f_hi(v3)))
                + ((b2f_hi(v4) + b2f_hi(v5)) + (b2f_hi(v6) + b2f_hi(v7)));
        }
        for (; j + 4 <= d64; j += 4) {
            int s0 = __shfl(myc, j + 0), s1 = __shfl(myc, j + 1);
            int s2 = __shfl(myc, j + 2), s3 = __shfl(myc, j + 3);
            unsigned v0 = *(const unsigned*)&h[(size_t)s0 * D + lane * 2];
            unsigned v1 = *(const unsigned*)&h[(size_t)s1 * D + lane * 2];
            unsigned v2 = *(const unsigned*)&h[(size_t)s2 * D + lane * 2];
            unsigned v3 = *(const unsigned*)&h[(size_t)s3 * D + lane * 2];
            ax += (b2f_lo(v0) + b2f_lo(v1)) + (b2f_lo(v2) + b2f_lo(v3));
            ay += (b2f_hi(v0) + b2f_hi(v1)) + (b2f_hi(v2) + b2f_hi(v3));
        }
        for (; j < d64; ++j) {
            int s = __shfl(myc, j);
            unsigned v = *(const unsigned*)&h[(size_t)s * D + lane * 2];
            ax += b2f_lo(v);
            ay += b2f_hi(v);
        }
        for (int t = beg + 64; t < end; ++t) {  // rare deg>64 tail
            int s = col[t];
            unsigned v = *(const unsigned*)&h[(size_t)s * D + lane * 2];
            ax += b2f_lo(v);
            ay += b2f_hi(v);
        }
        float inv = 1.0f / fmaxf((float)deg, 1.0f);
        unsigned o = (unsigned)f2b(ax * inv) | ((unsigned)f2b(ay * inv) << 16);
        *(unsigned*)&An[(wid * 16 + r) * ANSTR + lane * 2] = o;
        beg = begN; end = endN; deg = degN; myc = mycN;
    }
    // no barrier: An region is wave-private; compiler inserts lgkmcnt waits.

    // ---- phase 2: MFMA ----
    int l15 = lane & 15;
    int kq = lane >> 4;
    int rowC = min(rowBase + l15, N - 1);
    const unsigned short* anBase = &An[(wid * 16 + l15) * ANSTR + kq * 8];

    f32x4 acc[8];
#pragma unroll
    for (int r = 0; r < 8; ++r) acc[r] = (f32x4){0.f, 0.f, 0.f, 0.f};

#pragma unroll
    for (int s = 0; s < 8; ++s) {
        short8 av;
        if (s < 4) av = *(const short8*)&h[(size_t)rowC * D + s * 32 + kq * 8];
        else       av = *(const short8*)&anBase[(s - 4) * 32];
#pragma unroll
        for (int r = 0; r < 8; ++r) {
            short8 bv = *(const short8*)&Wt[(r * 16 + l15) * 256 + s * 32 + kq * 8];
            acc[r] = __builtin_amdgcn_mfma_f32_16x16x32_bf16(bv, av, acc[r], 0, 0, 0);
        }
    }

    // ---- epilogue ----
    int row = rowBase + l15;
    if (mode == 0) {
        if (row < N) {
#pragma unroll
            for (int r = 0; r < 8; ++r) {
                int c = r * 16 + kq * 4;
                float4 bb = *(const float4*)&bias[c];
                float v0 = fmaxf(acc[r][0] + bb.x, 0.f);
                float v1 = fmaxf(acc[r][1] + bb.y, 0.f);
                float v2 = fmaxf(acc[r][2] + bb.z, 0.f);
                float v3 = fmaxf(acc[r][3] + bb.w, 0.f);
                short4v o;
                o[0] = (short)f2b(v0); o[1] = (short)f2b(v1);
                o[2] = (short)f2b(v2); o[3] = (short)f2b(v3);
                *(short4v*)&out_h[(size_t)row * D + c] = o;
            }
        }
    } else {
        float s0 = 0.f, s1 = 0.f, q0 = 0.f, q1 = 0.f;
#pragma unroll
        for (int r = 0; r < 8; ++r) {
            int c = r * 16 + kq * 4;
            float4 bb = *(const float4*)&bias[c];
#pragma unroll
            for (int jj = 0; jj < 4; ++jj) {
                float v = fmaxf(acc[r][jj] + ((const float*)&bb)[jj], 0.f);  // relu(h2)
                float2 ws = *(const float2*)&Ws2[(c + jj) * 2];
                float2 wn = *(const float2*)&Wn2[(c + jj) * 2];
                s0 += v * ws.x; s1 += v * ws.y;
                q0 += v * wn.x; q1 += v * wn.y;
            }
        }
        // reduce over the 4 kq-lanes holding this row (lanes l15+16*kq)
        s0 += __shfl_xor(s0, 16); s1 += __shfl_xor(s1, 16);
        q0 += __shfl_xor(q0, 16); q1 += __shfl_xor(q1, 16);
        s0 += __shfl_xor(s0, 32); s1 += __shfl_xor(s1, 32);
        q0 += __shfl_xor(q0, 32); q1 += __shfl_xor(q1, 32);
        if (kq == 0 && row < N) {
            out_final[row * 2 + 0] = s0 + b2[0];
            out_final[row * 2 + 1] = s1 + b2[1];
            p[row * 2 + 0] = q0;
            p[row * 2 + 1] = q1;
        }
    }
}

// ---------------- final neighbor aggregation of projected p ----------------

__global__ __launch_bounds__(256) void k_l2agg(const float* __restrict__ p,
                                               const int* __restrict__ row_ptr,
                                               const int* __restrict__ col,
                                               float* __restrict__ out, int N) {
    int n = blockIdx.x * 256 + threadIdx.x;
    if (n >= N) return;
    int beg = row_ptr[n], end = row_ptr[n + 1];
    float a0 = 0.f, a1 = 0.f;
    for (int j = beg; j < end; ++j) {
        int s = col[j];
        float2 v = *(const float2*)&p[(size_t)s * 2];
        a0 += v.x;
        a1 += v.y;
    }
    float inv = 1.0f / fmaxf((float)(end - beg), 1.0f);
    out[n * 2 + 0] += a0 * inv;
    out[n * 2 + 1] += a1 * inv;
}

// ---------------- launch ----------------

extern "C" void kernel_launch(void* const* d_in, const int* in_sizes, int n_in,
                              void* d_out, int out_size, void* d_ws, size_t ws_size,
                              hipStream_t stream) {
    const float* x   = (const float*)d_in[0];
    const int*   src = (const int*)d_in[1];
    const int*   dst = (const int*)d_in[2];
    const float* Ws0 = (const float*)d_in[3];
    const float* Wn0 = (const float*)d_in[4];
    const float* b0  = (const float*)d_in[5];
    const float* Ws1 = (const float*)d_in[6];
    const float* Wn1 = (const float*)d_in[7];
    const float* b1  = (const float*)d_in[8];
    const float* Ws2 = (const float*)d_in[9];
    const float* Wn2 = (const float*)d_in[10];
    const float* b2  = (const float*)d_in[11];
    float* out = (float*)d_out;

    int N = in_sizes[0] / D;  // 50000
    int E = in_sizes[1];      // 600000
    size_t NB = (size_t)N * D;

    unsigned short* B0 = (unsigned short*)d_ws;   // xb
    unsigned short* B1 = B0 + NB;                 // h1r
    unsigned short* WT0 = B1 + NB;                // 128*256 bf16
    unsigned short* WT1 = WT0 + 128 * 256;
    float* p = (float*)(WT1 + 128 * 256);         // [N][2] f32
    int* row_ptr = (int*)(p + 2 * (size_t)N);     // N+1
    int* cnt     = row_ptr + (N + 2);
    int* partial = cnt + N;
    int* col     = partial + 64;                  // E

    // 1) zero degree counters
    hipMemsetAsync(cnt, 0, (size_t)N * sizeof(int), stream);

    // 2) combined prep (x->bf16, W0/W1 transpose) + degree count
    int nConvBlocks = (int)((NB / 8 + 255) / 256);
    int countBlocks = (E + 255) / 256;
    k_prep_count<<<nConvBlocks + 256 + countBlocks, 256, 0, stream>>>(
        x, B0, (int)NB, nConvBlocks, Ws0, Wn0, Ws1, Wn1, WT0, WT1, dst, cnt, E);

    // 3-5) CSR scan + fill
    int nChunks = (N + 2047) / 2048;
    k_scan_chunk<<<nChunks, 256, 0, stream>>>(cnt, row_ptr, partial, N);
    k_scan_add<<<nChunks, 256, 0, stream>>>(row_ptr, cnt, partial, N, nChunks);
    k_fill<<<countBlocks, 256, 0, stream>>>(src, dst, cnt, col, E);

    int fusedGrid = (N + 63) / 64;

    // 6) layer 0: h1r = relu(x@Ws0 + mean(x)@Wn0 + b0)
    k_fused<<<fusedGrid, 256, 0, stream>>>(B0, row_ptr, col, WT0, b0, B1,
                                           nullptr, nullptr, nullptr, nullptr, nullptr,
                                           N, 0);

    // 7) layer 1 + layer 2 projection: out_self = relu(h2)@Ws2+b2, p = relu(h2)@Wn2
    k_fused<<<fusedGrid, 256, 0, stream>>>(B1, row_ptr, col, WT1, b1, nullptr,
                                           Ws2, Wn2, b2, out, p,
                                           N, 1);

    // 8) out += mean-agg(p)
    k_l2agg<<<(N + 255) / 256, 256, 0, stream>>>(p, row_ptr, col, out, N);
}

// Round 6
// 179.766 us; speedup vs baseline: 1.4325x; 1.4325x over previous
//
#include <hip/hip_runtime.h>

#define D 128
#define KSTR 264  // W row stride in shorts: 528B, 4-mod-32 bank class (bank-conflict-free, proven r2-4)

typedef __attribute__((ext_vector_type(8))) short short8;
typedef __attribute__((ext_vector_type(4))) short short4v;
typedef __attribute__((ext_vector_type(4))) float f32x4;

// f32 -> bf16 round-to-nearest-even
__device__ inline unsigned short f2b(float f) {
    unsigned u = __float_as_uint(f);
    u += 0x7FFFu + ((u >> 16) & 1u);
    return (unsigned short)(u >> 16);
}
__device__ inline float b2f_lo(unsigned v) { return __uint_as_float(v << 16); }
__device__ inline float b2f_hi(unsigned v) { return __uint_as_float(v & 0xFFFF0000u); }

// ---------------- combined prep (x->bf16, W transpose) + degree count ----------------

__global__ __launch_bounds__(256) void k_prep_count(
        const float* __restrict__ x, unsigned short* __restrict__ xb, int n,
        int nConvBlocks,
        const float* __restrict__ Ws0, const float* __restrict__ Wn0,
        const float* __restrict__ Ws1, const float* __restrict__ Wn1,
        unsigned short* __restrict__ WT0, unsigned short* __restrict__ WT1,
        const int* __restrict__ dst, int* __restrict__ cnt, int E) {
    int bid = blockIdx.x;
    if (bid < nConvBlocks) {
        int i = (bid * 256 + threadIdx.x) * 8;
        if (i >= n) return;
        float4 a = *(const float4*)&x[i];
        float4 b = *(const float4*)&x[i + 4];
        short8 v;
        v[0] = (short)f2b(a.x); v[1] = (short)f2b(a.y);
        v[2] = (short)f2b(a.z); v[3] = (short)f2b(a.w);
        v[4] = (short)f2b(b.x); v[5] = (short)f2b(b.y);
        v[6] = (short)f2b(b.z); v[7] = (short)f2b(b.w);
        *(short8*)&xb[i] = v;
    } else if (bid < nConvBlocks + 256) {
        int idx = (bid - nConvBlocks) * 256 + threadIdx.x;  // 0..65535
        int layer = idx >> 15;
        int r = idx & 32767;
        int k = r >> 7;
        int nn = r & 127;
        const float* Ws = layer ? Ws1 : Ws0;
        const float* Wn = layer ? Wn1 : Wn0;
        unsigned short* Wt = layer ? WT1 : WT0;
        float v = (k < 128) ? Ws[k * 128 + nn] : Wn[(k - 128) * 128 + nn];
        Wt[nn * KSTR + k] = f2b(v);
    } else {
        int e = (bid - nConvBlocks - 256) * 256 + threadIdx.x;
        if (e < E) atomicAdd(&cnt[dst[e]], 1);
    }
}

// ---------------- CSR scan + fill ----------------

__global__ __launch_bounds__(256) void k_scan_chunk(const int* __restrict__ cnt,
                                                    int* __restrict__ row_ptr,
                                                    int* __restrict__ partial, int N) {
    __shared__ int s[256];
    int t = threadIdx.x;
    int base = blockIdx.x * 2048 + t * 8;
    int v[8];
    int sum = 0;
#pragma unroll
    for (int i = 0; i < 8; ++i) {
        v[i] = sum;
        int idx = base + i;
        sum += (idx < N) ? cnt[idx] : 0;
    }
    s[t] = sum;
    __syncthreads();
    for (int off = 1; off < 256; off <<= 1) {
        int x = (t >= off) ? s[t - off] : 0;
        __syncthreads();
        s[t] += x;
        __syncthreads();
    }
    int exc = s[t] - sum;
#pragma unroll
    for (int i = 0; i < 8; ++i) {
        int idx = base + i;
        if (idx < N) row_ptr[idx] = exc + v[i];
    }
    if (t == 255) partial[blockIdx.x] = s[255];
}

__global__ __launch_bounds__(256) void k_scan_add(int* __restrict__ row_ptr,
                                                  int* __restrict__ cnt,
                                                  const int* __restrict__ partial,
                                                  int N, int nChunks) {
    __shared__ int soff;
    int chunk = blockIdx.x;
    if (threadIdx.x == 0) {
        int o = 0;
        for (int j = 0; j < chunk; ++j) o += partial[j];
        soff = o;
    }
    __syncthreads();
    int off = soff;
    int lo = chunk * 2048;
    int hi = (chunk + 1) * 2048; if (hi > N) hi = N;
    for (int i = lo + threadIdx.x; i < hi; i += 256) {
        int v = row_ptr[i] + off;
        row_ptr[i] = v;
        cnt[i] = v;  // cursor copy for k_fill
    }
    if (chunk == nChunks - 1 && threadIdx.x == 0) row_ptr[N] = off + partial[chunk];
}

__global__ __launch_bounds__(256) void k_fill(const int* __restrict__ src,
                                              const int* __restrict__ dst,
                                              int* __restrict__ cnt,
                                              int* __restrict__ col, int E) {
    int e = blockIdx.x * 256 + threadIdx.x;
    if (e >= E) return;
    int p = atomicAdd(&cnt[dst[e]], 1);
    col[p] = src[e];
}

// ---------------- mean aggregation, bf16 in/out: one wave per node (max TLP) ----------------

__global__ __launch_bounds__(256) void k_agg_b(const unsigned short* __restrict__ h,
                                               const int* __restrict__ row_ptr,
                                               const int* __restrict__ col,
                                               unsigned short* __restrict__ hn, int N) {
    int w = (blockIdx.x * 256 + threadIdx.x) >> 6;
    int lane = threadIdx.x & 63;
    if (w >= N) return;
    int beg = row_ptr[w], end = row_ptr[w + 1];
    int deg = end - beg;
    int myc = (lane < deg) ? col[beg + lane] : 0;
    int d64 = min(deg, 64);
    float ax = 0.f, ay = 0.f;
    int j = 0;
    for (; j + 8 <= d64; j += 8) {
        int s0 = __shfl(myc, j + 0), s1 = __shfl(myc, j + 1);
        int s2 = __shfl(myc, j + 2), s3 = __shfl(myc, j + 3);
        int s4 = __shfl(myc, j + 4), s5 = __shfl(myc, j + 5);
        int s6 = __shfl(myc, j + 6), s7 = __shfl(myc, j + 7);
        unsigned v0 = *(const unsigned*)&h[(size_t)s0 * D + lane * 2];
        unsigned v1 = *(const unsigned*)&h[(size_t)s1 * D + lane * 2];
        unsigned v2 = *(const unsigned*)&h[(size_t)s2 * D + lane * 2];
        unsigned v3 = *(const unsigned*)&h[(size_t)s3 * D + lane * 2];
        unsigned v4 = *(const unsigned*)&h[(size_t)s4 * D + lane * 2];
        unsigned v5 = *(const unsigned*)&h[(size_t)s5 * D + lane * 2];
        unsigned v6 = *(const unsigned*)&h[(size_t)s6 * D + lane * 2];
        unsigned v7 = *(const unsigned*)&h[(size_t)s7 * D + lane * 2];
        ax += ((b2f_lo(v0) + b2f_lo(v1)) + (b2f_lo(v2) + b2f_lo(v3)))
            + ((b2f_lo(v4) + b2f_lo(v5)) + (b2f_lo(v6) + b2f_lo(v7)));
        ay += ((b2f_hi(v0) + b2f_hi(v1)) + (b2f_hi(v2) + b2f_hi(v3)))
            + ((b2f_hi(v4) + b2f_hi(v5)) + (b2f_hi(v6) + b2f_hi(v7)));
    }
    for (; j + 4 <= d64; j += 4) {
        int s0 = __shfl(myc, j + 0), s1 = __shfl(myc, j + 1);
        int s2 = __shfl(myc, j + 2), s3 = __shfl(myc, j + 3);
        unsigned v0 = *(const unsigned*)&h[(size_t)s0 * D + lane * 2];
        unsigned v1 = *(const unsigned*)&h[(size_t)s1 * D + lane * 2];
        unsigned v2 = *(const unsigned*)&h[(size_t)s2 * D + lane * 2];
        unsigned v3 = *(const unsigned*)&h[(size_t)s3 * D + lane * 2];
        ax += (b2f_lo(v0) + b2f_lo(v1)) + (b2f_lo(v2) + b2f_lo(v3));
        ay += (b2f_hi(v0) + b2f_hi(v1)) + (b2f_hi(v2) + b2f_hi(v3));
    }
    for (; j < d64; ++j) {
        int s = __shfl(myc, j);
        unsigned v = *(const unsigned*)&h[(size_t)s * D + lane * 2];
        ax += b2f_lo(v);
        ay += b2f_hi(v);
    }
    for (int t = beg + 64; t < end; ++t) {
        int s = col[t];
        unsigned v = *(const unsigned*)&h[(size_t)s * D + lane * 2];
        ax += b2f_lo(v);
        ay += b2f_hi(v);
    }
    float inv = 1.0f / fmaxf((float)deg, 1.0f);
    unsigned o = (unsigned)f2b(ax * inv) | ((unsigned)f2b(ay * inv) << 16);
    *(unsigned*)&hn[(size_t)w * D + lane * 2] = o;
}

// ---------------- MFMA SAGE GEMM, 128-row block, full-width waves ----------------
// Block = 4 waves x 32 rows = 128 rows. Wave covers ALL 128 output cols
// (8 B-frags reused across 2 row-frags -> 16 MFMA per {2 A-loads + 8 ds_read_b128}).
// Swapped mfma operands (validated r4): lane (l15,kq) holds data-row
// waveRow + m*16 + l15, cols r*16 + kq*4 + j.
// mode 0: out_h[row][c] = bf16(relu(gemm + bias))
// mode 1: v = relu(gemm + bias) (= h2, f32, never stored);
//         out_final[row] = v@Ws2 + b2 ; p[row] = v@Wn2  (kq-lane shfl reduce)

__global__ __launch_bounds__(256) void k_gemm2(
        const unsigned short* __restrict__ Ah,   // self rows [N][128]
        const unsigned short* __restrict__ An,   // neigh rows [N][128]
        const unsigned short* __restrict__ Wt,   // [128 n][KSTR] bf16, k<128 self / k>=128 neigh
        const float* __restrict__ bias,
        unsigned short* __restrict__ out_h,      // mode 0
        const float* __restrict__ Ws2,           // mode 1: [128][2]
        const float* __restrict__ Wn2,
        const float* __restrict__ b2,
        float* __restrict__ out_final,           // mode 1: [N][2]
        float* __restrict__ p,                   // mode 1: [N][2]
        int N, int mode) {
    __shared__ unsigned short Wl[128 * KSTR];  // 67584 B -> 2 blocks/CU
    int tid = threadIdx.x;
    for (int i = tid * 8; i < 128 * KSTR; i += 2048)
        *(short8*)&Wl[i] = *(const short8*)&Wt[i];

    int lane = tid & 63;
    int wid = tid >> 6;
    int l15 = lane & 15;
    int kq = lane >> 4;
    int waveRow = blockIdx.x * 128 + wid * 32;
    int r0c = min(waveRow + l15, N - 1);
    int r1c = min(waveRow + 16 + l15, N - 1);

    f32x4 acc[2][8];
#pragma unroll
    for (int m = 0; m < 2; ++m)
#pragma unroll
        for (int r = 0; r < 8; ++r) acc[m][r] = (f32x4){0.f, 0.f, 0.f, 0.f};

    __syncthreads();

    const unsigned short* lb = &Wl[l15 * KSTR + kq * 8];
#pragma unroll
    for (int s = 0; s < 8; ++s) {
        const unsigned short* A = (s < 4) ? Ah : An;
        int kk = (s & 3) * 32 + kq * 8;
        short8 a0 = *(const short8*)&A[(size_t)r0c * D + kk];
        short8 a1 = *(const short8*)&A[(size_t)r1c * D + kk];
#pragma unroll
        for (int r = 0; r < 8; ++r) {
            short8 bv = *(const short8*)&lb[s * 32 + r * (16 * KSTR)];
            acc[0][r] = __builtin_amdgcn_mfma_f32_16x16x32_bf16(bv, a0, acc[0][r], 0, 0, 0);
            acc[1][r] = __builtin_amdgcn_mfma_f32_16x16x32_bf16(bv, a1, acc[1][r], 0, 0, 0);
        }
    }

    if (mode == 0) {
#pragma unroll
        for (int m = 0; m < 2; ++m) {
            int row = waveRow + m * 16 + l15;
            if (row < N) {
#pragma unroll
                for (int r = 0; r < 8; ++r) {
                    int c = r * 16 + kq * 4;
                    float4 bb = *(const float4*)&bias[c];
                    float v0 = fmaxf(acc[m][r][0] + bb.x, 0.f);
                    float v1 = fmaxf(acc[m][r][1] + bb.y, 0.f);
                    float v2 = fmaxf(acc[m][r][2] + bb.z, 0.f);
                    float v3 = fmaxf(acc[m][r][3] + bb.w, 0.f);
                    short4v o;
                    o[0] = (short)f2b(v0); o[1] = (short)f2b(v1);
                    o[2] = (short)f2b(v2); o[3] = (short)f2b(v3);
                    *(short4v*)&out_h[(size_t)row * D + c] = o;
                }
            }
        }
    } else {
#pragma unroll
        for (int m = 0; m < 2; ++m) {
            float s0 = 0.f, s1 = 0.f, q0 = 0.f, q1 = 0.f;
#pragma unroll
            for (int r = 0; r < 8; ++r) {
                int c = r * 16 + kq * 4;
                float4 bb = *(const float4*)&bias[c];
#pragma unroll
                for (int jj = 0; jj < 4; ++jj) {
                    float v = fmaxf(acc[m][r][jj] + ((const float*)&bb)[jj], 0.f);
                    float2 ws = *(const float2*)&Ws2[(c + jj) * 2];
                    float2 wn = *(const float2*)&Wn2[(c + jj) * 2];
                    s0 += v * ws.x; s1 += v * ws.y;
                    q0 += v * wn.x; q1 += v * wn.y;
                }
            }
            s0 += __shfl_xor(s0, 16); s1 += __shfl_xor(s1, 16);
            q0 += __shfl_xor(q0, 16); q1 += __shfl_xor(q1, 16);
            s0 += __shfl_xor(s0, 32); s1 += __shfl_xor(s1, 32);
            q0 += __shfl_xor(q0, 32); q1 += __shfl_xor(q1, 32);
            int row = waveRow + m * 16 + l15;
            if (kq == 0 && row < N) {
                out_final[row * 2 + 0] = s0 + b2[0];
                out_final[row * 2 + 1] = s1 + b2[1];
                p[row * 2 + 0] = q0;
                p[row * 2 + 1] = q1;
            }
        }
    }
}

// ---------------- final neighbor aggregation of projected p ----------------

__global__ __launch_bounds__(256) void k_l2agg(const float* __restrict__ p,
                                               const int* __restrict__ row_ptr,
                                               const int* __restrict__ col,
                                               float* __restrict__ out, int N) {
    int n = blockIdx.x * 256 + threadIdx.x;
    if (n >= N) return;
    int beg = row_ptr[n], end = row_ptr[n + 1];
    float a0 = 0.f, a1 = 0.f;
    for (int j = beg; j < end; ++j) {
        int s = col[j];
        float2 v = *(const float2*)&p[(size_t)s * 2];
        a0 += v.x;
        a1 += v.y;
    }
    float inv = 1.0f / fmaxf((float)(end - beg), 1.0f);
    out[n * 2 + 0] += a0 * inv;
    out[n * 2 + 1] += a1 * inv;
}

// ---------------- launch ----------------

extern "C" void kernel_launch(void* const* d_in, const int* in_sizes, int n_in,
                              void* d_out, int out_size, void* d_ws, size_t ws_size,
                              hipStream_t stream) {
    const float* x   = (const float*)d_in[0];
    const int*   src = (const int*)d_in[1];
    const int*   dst = (const int*)d_in[2];
    const float* Ws0 = (const float*)d_in[3];
    const float* Wn0 = (const float*)d_in[4];
    const float* b0  = (const float*)d_in[5];
    const float* Ws1 = (const float*)d_in[6];
    const float* Wn1 = (const float*)d_in[7];
    const float* b1  = (const float*)d_in[8];
    const float* Ws2 = (const float*)d_in[9];
    const float* Wn2 = (const float*)d_in[10];
    const float* b2  = (const float*)d_in[11];
    float* out = (float*)d_out;

    int N = in_sizes[0] / D;  // 50000
    int E = in_sizes[1];      // 600000
    size_t NB = (size_t)N * D;

    unsigned short* B0 = (unsigned short*)d_ws;   // xb
    unsigned short* B1 = B0 + NB;                 // hn (both layers)
    unsigned short* B2 = B1 + NB;                 // h1
    unsigned short* WT0 = B2 + NB;                // 128*KSTR bf16
    unsigned short* WT1 = WT0 + 128 * KSTR;
    float* p = (float*)(WT1 + 128 * KSTR);        // [N][2] f32
    int* row_ptr = (int*)(p + 2 * (size_t)N);     // N+1
    int* cnt     = row_ptr + (N + 2);
    int* partial = cnt + N;
    int* col     = partial + 64;                  // E

    // 1) zero degree counters
    hipMemsetAsync(cnt, 0, (size_t)N * sizeof(int), stream);

    // 2) combined prep (x->bf16, W0/W1 transpose) + degree count
    int nConvBlocks = (int)((NB / 8 + 255) / 256);
    int countBlocks = (E + 255) / 256;
    k_prep_count<<<nConvBlocks + 256 + countBlocks, 256, 0, stream>>>(
        x, B0, (int)NB, nConvBlocks, Ws0, Wn0, Ws1, Wn1, WT0, WT1, dst, cnt, E);

    // 3-5) CSR scan + fill
    int nChunks = (N + 2047) / 2048;
    k_scan_chunk<<<nChunks, 256, 0, stream>>>(cnt, row_ptr, partial, N);
    k_scan_add<<<nChunks, 256, 0, stream>>>(row_ptr, cnt, partial, N, nChunks);
    k_fill<<<countBlocks, 256, 0, stream>>>(src, dst, cnt, col, E);

    int aggGrid  = (N * 64 + 255) / 256;  // one wave per node
    int gemmGrid = (N + 127) / 128;

    // 6-7) layer 0: h1 = relu(x@Ws0 + mean(x)@Wn0 + b0)
    k_agg_b<<<aggGrid, 256, 0, stream>>>(B0, row_ptr, col, B1, N);
    k_gemm2<<<gemmGrid, 256, 0, stream>>>(B0, B1, WT0, b0, B2,
                                          nullptr, nullptr, nullptr, nullptr, nullptr,
                                          N, 0);

    // 8-9) layer 1 (+ fused layer-2 projection): h2 in-register only
    k_agg_b<<<aggGrid, 256, 0, stream>>>(B2, row_ptr, col, B1, N);
    k_gemm2<<<gemmGrid, 256, 0, stream>>>(B2, B1, WT1, b1, nullptr,
                                          Ws2, Wn2, b2, out, p,
                                          N, 1);

    // 10) out += mean-agg(p)
    k_l2agg<<<(N + 255) / 256, 256, 0, stream>>>(p, row_ptr, col, out, N);
}

// Round 7
// 171.097 us; speedup vs baseline: 1.5050x; 1.0507x over previous
//
#include <hip/hip_runtime.h>

#define D 128
#define KSTR 264  // W row stride in shorts: 528B, 4-mod-32 bank class (bank-conflict-free, proven r2-6)

typedef __attribute__((ext_vector_type(8))) short short8;
typedef __attribute__((ext_vector_type(4))) short short4v;
typedef __attribute__((ext_vector_type(4))) float f32x4;

// f32 -> bf16 round-to-nearest-even
__device__ inline unsigned short f2b(float f) {
    unsigned u = __float_as_uint(f);
    u += 0x7FFFu + ((u >> 16) & 1u);
    return (unsigned short)(u >> 16);
}
__device__ inline float b2f_lo(unsigned v) { return __uint_as_float(v << 16); }
__device__ inline float b2f_hi(unsigned v) { return __uint_as_float(v & 0xFFFF0000u); }

// ---------------- combined prep (x->bf16, W transpose) + degree count ----------------

__global__ __launch_bounds__(256) void k_prep_count(
        const float* __restrict__ x, unsigned short* __restrict__ xb, int n,
        int nConvBlocks,
        const float* __restrict__ Ws0, const float* __restrict__ Wn0,
        const float* __restrict__ Ws1, const float* __restrict__ Wn1,
        unsigned short* __restrict__ WT0, unsigned short* __restrict__ WT1,
        const int* __restrict__ dst, int* __restrict__ cnt, int E) {
    int bid = blockIdx.x;
    if (bid < nConvBlocks) {
        int i = (bid * 256 + threadIdx.x) * 8;
        if (i >= n) return;
        float4 a = *(const float4*)&x[i];
        float4 b = *(const float4*)&x[i + 4];
        short8 v;
        v[0] = (short)f2b(a.x); v[1] = (short)f2b(a.y);
        v[2] = (short)f2b(a.z); v[3] = (short)f2b(a.w);
        v[4] = (short)f2b(b.x); v[5] = (short)f2b(b.y);
        v[6] = (short)f2b(b.z); v[7] = (short)f2b(b.w);
        *(short8*)&xb[i] = v;
    } else if (bid < nConvBlocks + 256) {
        int idx = (bid - nConvBlocks) * 256 + threadIdx.x;  // 0..65535
        int layer = idx >> 15;
        int r = idx & 32767;
        int k = r >> 7;
        int nn = r & 127;
        const float* Ws = layer ? Ws1 : Ws0;
        const float* Wn = layer ? Wn1 : Wn0;
        unsigned short* Wt = layer ? WT1 : WT0;
        float v = (k < 128) ? Ws[k * 128 + nn] : Wn[(k - 128) * 128 + nn];
        Wt[nn * KSTR + k] = f2b(v);
    } else {
        int e = (bid - nConvBlocks - 256) * 256 + threadIdx.x;
        if (e < E) atomicAdd(&cnt[dst[e]], 1);
    }
}

// ---------------- CSR scan + fill ----------------

__global__ __launch_bounds__(256) void k_scan_chunk(const int* __restrict__ cnt,
                                                    int* __restrict__ row_ptr,
                                                    int* __restrict__ partial, int N) {
    __shared__ int s[256];
    int t = threadIdx.x;
    int base = blockIdx.x * 2048 + t * 8;
    int v[8];
    int sum = 0;
#pragma unroll
    for (int i = 0; i < 8; ++i) {
        v[i] = sum;
        int idx = base + i;
        sum += (idx < N) ? cnt[idx] : 0;
    }
    s[t] = sum;
    __syncthreads();
    for (int off = 1; off < 256; off <<= 1) {
        int x = (t >= off) ? s[t - off] : 0;
        __syncthreads();
        s[t] += x;
        __syncthreads();
    }
    int exc = s[t] - sum;
#pragma unroll
    for (int i = 0; i < 8; ++i) {
        int idx = base + i;
        if (idx < N) row_ptr[idx] = exc + v[i];
    }
    if (t == 255) partial[blockIdx.x] = s[255];
}

__global__ __launch_bounds__(256) void k_scan_add(int* __restrict__ row_ptr,
                                                  int* __restrict__ cnt,
                                                  const int* __restrict__ partial,
                                                  int N, int nChunks) {
    __shared__ int soff;
    int chunk = blockIdx.x;
    if (threadIdx.x == 0) {
        int o = 0;
        for (int j = 0; j < chunk; ++j) o += partial[j];
        soff = o;
    }
    __syncthreads();
    int off = soff;
    int lo = chunk * 2048;
    int hi = (chunk + 1) * 2048; if (hi > N) hi = N;
    for (int i = lo + threadIdx.x; i < hi; i += 256) {
        int v = row_ptr[i] + off;
        row_ptr[i] = v;
        cnt[i] = v;  // cursor copy for k_fill
    }
    if (chunk == nChunks - 1 && threadIdx.x == 0) row_ptr[N] = off + partial[chunk];
}

__global__ __launch_bounds__(256) void k_fill(const int* __restrict__ src,
                                              const int* __restrict__ dst,
                                              int* __restrict__ cnt,
                                              int* __restrict__ col, int E) {
    int e = blockIdx.x * 256 + threadIdx.x;
    if (e >= E) return;
    int p = atomicAdd(&cnt[dst[e]], 1);
    col[p] = src[e];
}

// ---------------- mean aggregation, bf16 in/out: one wave per node (max TLP) ----------------

__global__ __launch_bounds__(256) void k_agg_b(const unsigned short* __restrict__ h,
                                               const int* __restrict__ row_ptr,
                                               const int* __restrict__ col,
                                               unsigned short* __restrict__ hn, int N) {
    int w = (blockIdx.x * 256 + threadIdx.x) >> 6;
    int lane = threadIdx.x & 63;
    if (w >= N) return;
    int beg = row_ptr[w], end = row_ptr[w + 1];
    int deg = end - beg;
    int myc = (lane < deg) ? col[beg + lane] : 0;
    int d64 = min(deg, 64);
    float ax = 0.f, ay = 0.f;
    int j = 0;
    for (; j + 8 <= d64; j += 8) {
        int s0 = __shfl(myc, j + 0), s1 = __shfl(myc, j + 1);
        int s2 = __shfl(myc, j + 2), s3 = __shfl(myc, j + 3);
        int s4 = __shfl(myc, j + 4), s5 = __shfl(myc, j + 5);
        int s6 = __shfl(myc, j + 6), s7 = __shfl(myc, j + 7);
        unsigned v0 = *(const unsigned*)&h[(size_t)s0 * D + lane * 2];
        unsigned v1 = *(const unsigned*)&h[(size_t)s1 * D + lane * 2];
        unsigned v2 = *(const unsigned*)&h[(size_t)s2 * D + lane * 2];
        unsigned v3 = *(const unsigned*)&h[(size_t)s3 * D + lane * 2];
        unsigned v4 = *(const unsigned*)&h[(size_t)s4 * D + lane * 2];
        unsigned v5 = *(const unsigned*)&h[(size_t)s5 * D + lane * 2];
        unsigned v6 = *(const unsigned*)&h[(size_t)s6 * D + lane * 2];
        unsigned v7 = *(const unsigned*)&h[(size_t)s7 * D + lane * 2];
        ax += ((b2f_lo(v0) + b2f_lo(v1)) + (b2f_lo(v2) + b2f_lo(v3)))
            + ((b2f_lo(v4) + b2f_lo(v5)) + (b2f_lo(v6) + b2f_lo(v7)));
        ay += ((b2f_hi(v0) + b2f_hi(v1)) + (b2f_hi(v2) + b2f_hi(v3)))
            + ((b2f_hi(v4) + b2f_hi(v5)) + (b2f_hi(v6) + b2f_hi(v7)));
    }
    for (; j + 4 <= d64; j += 4) {
        int s0 = __shfl(myc, j + 0), s1 = __shfl(myc, j + 1);
        int s2 = __shfl(myc, j + 2), s3 = __shfl(myc, j + 3);
        unsigned v0 = *(const unsigned*)&h[(size_t)s0 * D + lane * 2];
        unsigned v1 = *(const unsigned*)&h[(size_t)s1 * D + lane * 2];
        unsigned v2 = *(const unsigned*)&h[(size_t)s2 * D + lane * 2];
        unsigned v3 = *(const unsigned*)&h[(size_t)s3 * D + lane * 2];
        ax += (b2f_lo(v0) + b2f_lo(v1)) + (b2f_lo(v2) + b2f_lo(v3));
        ay += (b2f_hi(v0) + b2f_hi(v1)) + (b2f_hi(v2) + b2f_hi(v3));
    }
    for (; j < d64; ++j) {
        int s = __shfl(myc, j);
        unsigned v = *(const unsigned*)&h[(size_t)s * D + lane * 2];
        ax += b2f_lo(v);
        ay += b2f_hi(v);
    }
    for (int t = beg + 64; t < end; ++t) {
        int s = col[t];
        unsigned v = *(const unsigned*)&h[(size_t)s * D + lane * 2];
        ax += b2f_lo(v);
        ay += b2f_hi(v);
    }
    float inv = 1.0f / fmaxf((float)deg, 1.0f);
    unsigned o = (unsigned)f2b(ax * inv) | ((unsigned)f2b(ay * inv) << 16);
    *(unsigned*)&hn[(size_t)w * D + lane * 2] = o;
}

// ---------------- MFMA SAGE GEMM, 128-row block, full-width waves ----------------
// A-latency fix (r7): ALL 16 A-fragment loads issued at kernel top, so their
// global latency overlaps the W LDS-staging + barrier; k-loop is pure LDS+MFMA.
// Swapped mfma operands (validated r4): lane (l15,kq) holds data-row
// waveRow + m*16 + l15, cols r*16 + kq*4 + j.
// mode 0: out_h[row][c] = bf16(relu(gemm + bias))
// mode 1: v = relu(gemm + bias) (= h2, f32, never stored);
//         out_final[row] = v@Ws2 + b2 ; p[row] = v@Wn2  (kq-lane shfl reduce)

__global__ __launch_bounds__(256, 2) void k_gemm2(
        const unsigned short* __restrict__ Ah,   // self rows [N][128]
        const unsigned short* __restrict__ An,   // neigh rows [N][128]
        const unsigned short* __restrict__ Wt,   // [128 n][KSTR] bf16, k<128 self / k>=128 neigh
        const float* __restrict__ bias,
        unsigned short* __restrict__ out_h,      // mode 0
        const float* __restrict__ Ws2,           // mode 1: [128][2]
        const float* __restrict__ Wn2,
        const float* __restrict__ b2,
        float* __restrict__ out_final,           // mode 1: [N][2]
        float* __restrict__ p,                   // mode 1: [N][2]
        int N, int mode) {
    __shared__ unsigned short Wl[128 * KSTR];  // 67584 B -> 2 blocks/CU
    int tid = threadIdx.x;
    int lane = tid & 63;
    int wid = tid >> 6;
    int l15 = lane & 15;
    int kq = lane >> 4;
    int waveRow = blockIdx.x * 128 + wid * 32;
    int r0c = min(waveRow + l15, N - 1);
    int r1c = min(waveRow + 16 + l15, N - 1);

    // ---- issue ALL A-fragment loads first: latency hides under W staging ----
    short8 a0[8], a1[8];
#pragma unroll
    for (int s = 0; s < 8; ++s) {
        const unsigned short* A = (s < 4) ? Ah : An;
        int kk = (s & 3) * 32 + kq * 8;
        a0[s] = *(const short8*)&A[(size_t)r0c * D + kk];
        a1[s] = *(const short8*)&A[(size_t)r1c * D + kk];
    }

    // ---- stage W into LDS (linear, conflict-free b128) ----
    for (int i = tid * 8; i < 128 * KSTR; i += 2048)
        *(short8*)&Wl[i] = *(const short8*)&Wt[i];

    f32x4 acc[2][8];
#pragma unroll
    for (int m = 0; m < 2; ++m)
#pragma unroll
        for (int r = 0; r < 8; ++r) acc[m][r] = (f32x4){0.f, 0.f, 0.f, 0.f};

    __syncthreads();

    // ---- pure LDS + MFMA k-loop ----
    const unsigned short* lb = &Wl[l15 * KSTR + kq * 8];
#pragma unroll
    for (int s = 0; s < 8; ++s) {
#pragma unroll
        for (int r = 0; r < 8; ++r) {
            short8 bv = *(const short8*)&lb[s * 32 + r * (16 * KSTR)];
            acc[0][r] = __builtin_amdgcn_mfma_f32_16x16x32_bf16(bv, a0[s], acc[0][r], 0, 0, 0);
            acc[1][r] = __builtin_amdgcn_mfma_f32_16x16x32_bf16(bv, a1[s], acc[1][r], 0, 0, 0);
        }
    }

    if (mode == 0) {
#pragma unroll
        for (int m = 0; m < 2; ++m) {
            int row = waveRow + m * 16 + l15;
            if (row < N) {
#pragma unroll
                for (int r = 0; r < 8; ++r) {
                    int c = r * 16 + kq * 4;
                    float4 bb = *(const float4*)&bias[c];
                    float v0 = fmaxf(acc[m][r][0] + bb.x, 0.f);
                    float v1 = fmaxf(acc[m][r][1] + bb.y, 0.f);
                    float v2 = fmaxf(acc[m][r][2] + bb.z, 0.f);
                    float v3 = fmaxf(acc[m][r][3] + bb.w, 0.f);
                    short4v o;
                    o[0] = (short)f2b(v0); o[1] = (short)f2b(v1);
                    o[2] = (short)f2b(v2); o[3] = (short)f2b(v3);
                    *(short4v*)&out_h[(size_t)row * D + c] = o;
                }
            }
        }
    } else {
#pragma unroll
        for (int m = 0; m < 2; ++m) {
            float s0 = 0.f, s1 = 0.f, q0 = 0.f, q1 = 0.f;
#pragma unroll
            for (int r = 0; r < 8; ++r) {
                int c = r * 16 + kq * 4;
                float4 bb = *(const float4*)&bias[c];
#pragma unroll
                for (int jj = 0; jj < 4; ++jj) {
                    float v = fmaxf(acc[m][r][jj] + ((const float*)&bb)[jj], 0.f);
                    float2 ws = *(const float2*)&Ws2[(c + jj) * 2];
                    float2 wn = *(const float2*)&Wn2[(c + jj) * 2];
                    s0 += v * ws.x; s1 += v * ws.y;
                    q0 += v * wn.x; q1 += v * wn.y;
                }
            }
            s0 += __shfl_xor(s0, 16); s1 += __shfl_xor(s1, 16);
            q0 += __shfl_xor(q0, 16); q1 += __shfl_xor(q1, 16);
            s0 += __shfl_xor(s0, 32); s1 += __shfl_xor(s1, 32);
            q0 += __shfl_xor(q0, 32); q1 += __shfl_xor(q1, 32);
            int row = waveRow + m * 16 + l15;
            if (kq == 0 && row < N) {
                out_final[row * 2 + 0] = s0 + b2[0];
                out_final[row * 2 + 1] = s1 + b2[1];
                p[row * 2 + 0] = q0;
                p[row * 2 + 1] = q1;
            }
        }
    }
}

// ---------------- final neighbor aggregation of projected p ----------------

__global__ __launch_bounds__(256) void k_l2agg(const float* __restrict__ p,
                                               const int* __restrict__ row_ptr,
                                               const int* __restrict__ col,
                                               float* __restrict__ out, int N) {
    int n = blockIdx.x * 256 + threadIdx.x;
    if (n >= N) return;
    int beg = row_ptr[n], end = row_ptr[n + 1];
    float a0 = 0.f, a1 = 0.f;
    for (int j = beg; j < end; ++j) {
        int s = col[j];
        float2 v = *(const float2*)&p[(size_t)s * 2];
        a0 += v.x;
        a1 += v.y;
    }
    float inv = 1.0f / fmaxf((float)(end - beg), 1.0f);
    out[n * 2 + 0] += a0 * inv;
    out[n * 2 + 1] += a1 * inv;
}

// ---------------- launch ----------------

extern "C" void kernel_launch(void* const* d_in, const int* in_sizes, int n_in,
                              void* d_out, int out_size, void* d_ws, size_t ws_size,
                              hipStream_t stream) {
    const float* x   = (const float*)d_in[0];
    const int*   src = (const int*)d_in[1];
    const int*   dst = (const int*)d_in[2];
    const float* Ws0 = (const float*)d_in[3];
    const float* Wn0 = (const float*)d_in[4];
    const float* b0  = (const float*)d_in[5];
    const float* Ws1 = (const float*)d_in[6];
    const float* Wn1 = (const float*)d_in[7];
    const float* b1  = (const float*)d_in[8];
    const float* Ws2 = (const float*)d_in[9];
    const float* Wn2 = (const float*)d_in[10];
    const float* b2  = (const float*)d_in[11];
    float* out = (float*)d_out;

    int N = in_sizes[0] / D;  // 50000
    int E = in_sizes[1];      // 600000
    size_t NB = (size_t)N * D;

    unsigned short* B0 = (unsigned short*)d_ws;   // xb
    unsigned short* B1 = B0 + NB;                 // hn (both layers)
    unsigned short* B2 = B1 + NB;                 // h1
    unsigned short* WT0 = B2 + NB;                // 128*KSTR bf16
    unsigned short* WT1 = WT0 + 128 * KSTR;
    float* p = (float*)(WT1 + 128 * KSTR);        // [N][2] f32
    int* row_ptr = (int*)(p + 2 * (size_t)N);     // N+1
    int* cnt     = row_ptr + (N + 2);
    int* partial = cnt + N;
    int* col     = partial + 64;                  // E

    // 1) zero degree counters
    hipMemsetAsync(cnt, 0, (size_t)N * sizeof(int), stream);

    // 2) combined prep (x->bf16, W0/W1 transpose) + degree count
    int nConvBlocks = (int)((NB / 8 + 255) / 256);
    int countBlocks = (E + 255) / 256;
    k_prep_count<<<nConvBlocks + 256 + countBlocks, 256, 0, stream>>>(
        x, B0, (int)NB, nConvBlocks, Ws0, Wn0, Ws1, Wn1, WT0, WT1, dst, cnt, E);

    // 3-5) CSR scan + fill
    int nChunks = (N + 2047) / 2048;
    k_scan_chunk<<<nChunks, 256, 0, stream>>>(cnt, row_ptr, partial, N);
    k_scan_add<<<nChunks, 256, 0, stream>>>(row_ptr, cnt, partial, N, nChunks);
    k_fill<<<countBlocks, 256, 0, stream>>>(src, dst, cnt, col, E);

    int aggGrid  = (N * 64 + 255) / 256;  // one wave per node
    int gemmGrid = (N + 127) / 128;

    // 6-7) layer 0: h1 = relu(x@Ws0 + mean(x)@Wn0 + b0)
    k_agg_b<<<aggGrid, 256, 0, stream>>>(B0, row_ptr, col, B1, N);
    k_gemm2<<<gemmGrid, 256, 0, stream>>>(B0, B1, WT0, b0, B2,
                                          nullptr, nullptr, nullptr, nullptr, nullptr,
                                          N, 0);

    // 8-9) layer 1 (+ fused layer-2 projection): h2 in-register only
    k_agg_b<<<aggGrid, 256, 0, stream>>>(B2, row_ptr, col, B1, N);
    k_gemm2<<<gemmGrid, 256, 0, stream>>>(B2, B1, WT1, b1, nullptr,
                                          Ws2, Wn2, b2, out, p,
                                          N, 1);

    // 10) out += mean-agg(p)
    k_l2agg<<<(N + 255) / 256, 256, 0, stream>>>(p, row_ptr, col, out, N);
}